// Round 7
// baseline (273.263 us; speedup 1.0000x reference)
//
#include <hip/hip_runtime.h>
#include <math.h>

// Sampler: B=256 rows, V=128256 vocab.
// out[b] = (T[b]==0) ? argmax(logits[b,:])
//                    : argmax(logits[b,:]/T[b] - log(-log1p(-noise[b,:])))
// Log-space Gumbel-max (softmax denom + row-max cancel), all in log2 so each
// log is one HW v_log_f32.
//
// R10 post-mortem: hybrid VGPR-nt + LDS-DMA = 250.3 vs R9's 245.5 -> the
// outstanding-request pool is SHARED across paths.  Axis tally at ~3.5 TB/s
// effective read: depth-null (R6/R9), path-null (R10), source-mix-null
// (all-L3-hit dispatches run the same speed).  One axis never isolated:
// cache-allocation mode.  nt = non-temporal at BOTH L1 and L2 -> every 64B
// line is an individually-tracked L2-miss with no L2 miss machinery
// (sector/merge) helping on the fabric.  The untested 2x2 corner is
// L1-bypass + L2-ALLOCATE -- old glc-load semantics, spelled sc0 on gfx950.
// Zero-reuse data makes L2 allocation harmless; L2's miss pipeline may
// restore fabric efficiency (babelstream-class reads need it).
// R11: R9 byte-identical, nt -> sc0 on all three load templates.
//   - pipeline: distance-3, vmcnt(6) sampled / vmcnt(3) greedy, exact;
//   - grid: TPB=256, CHUNKS=8, 2048 blocks = 8/CU, one round.

constexpr int TPB    = 256;
constexpr int CHUNKS = 8;

typedef float v4f __attribute__((ext_vector_type(4)));

__device__ __forceinline__ void amax_comb(float v, int i, float& bv, int& bi) {
    // np.argmax semantics: strictly greater wins; ties -> lowest index
    if (v > bv || (v == bv && i < bi)) { bv = v; bi = i; }
}

// key = l*c - log2(-log1p(-u)), c = invT/ln2.  Abs err ~1e-6, far below
// top-1/top-2 Gumbel key gaps.  u==0 -> en=0 -> -inf -> key=+inf, matching
// reference probs/0 = +inf (first-index tie-break both sides).
__device__ __forceinline__ float gumbel_key(float l, float u, float c) {
    // u >= 0.125: 1-u exact on the 2^-24 uniform grid, |log2(1-u)| >= 0.19
    const float w   = 1.0f - u;
    const float enw = __log2f(w) * -0.693147180559945f;   // -log(1-u)
    // u < 0.125: en/u = 1 + u/2 + u^2/3 + ... (trunc err < 6e-6 rel)
    float p = 0.16666667f;
    p = fmaf(p, u, 0.2f);
    p = fmaf(p, u, 0.25f);
    p = fmaf(p, u, 0.33333333f);
    p = fmaf(p, u, 0.5f);
    p = fmaf(p, u, 1.0f);
    const float en = (u < 0.125f) ? p * u : enw;
    return fmaf(l, c, -__log2f(en));
}

// Issue batch J: two async 16B sc0 loads into (LD, UD).  Opaque to the
// compiler: cannot be sunk, registers pinned.  sc0 = L1-bypass (old glc
// load semantics), L2 allocates and runs its miss machinery.
#define ISSUE2(LD, UD, J)                                               \
    {                                                                   \
        const int fi = min(t + (J) * TPB, last);                        \
        asm volatile("global_load_dwordx4 %0, %2, off sc0\n\t"          \
                     "global_load_dwordx4 %1, %3, off sc0"              \
                     : "=&v"(LD), "=&v"(UD)                             \
                     : "v"(lg4 + fi), "v"(nz4 + fi));                   \
    }

// Issue batch J: one async 16B sc0 load (greedy path, logits only).
#define ISSUE1(LD, J)                                                   \
    {                                                                   \
        const int fi = min(t + (J) * TPB, last);                        \
        asm volatile("global_load_dwordx4 %0, %1, off sc0"              \
                     : "=&v"(LD) : "v"(lg4 + fi));                      \
    }

// Counted wait: oldest loads retired, N newest still in flight.  The
// sched_barrier stops the compiler hoisting the consume VALU above the wait.
#define WAITV(N)                                                        \
    asm volatile("s_waitcnt vmcnt(" #N ")" ::: "memory");               \
    __builtin_amdgcn_sched_barrier(0)

// Consume batch JC from (LC, UC) -- sampled path.
#define CONS_S(LC, UC, JC)                                              \
    {                                                                   \
        const int f = t + (JC) * TPB;                                   \
        if (f < V4c) {                                                  \
            const int base = (gbase + f) << 2;                          \
            const float k0 = gumbel_key(LC.x, UC.x, c);                 \
            const float k1 = gumbel_key(LC.y, UC.y, c);                 \
            const float k2 = gumbel_key(LC.z, UC.z, c);                 \
            const float k3 = gumbel_key(LC.w, UC.w, c);                 \
            if (k0 > bv) { bv = k0; bi = base;     }                    \
            if (k1 > bv) { bv = k1; bi = base + 1; }                    \
            if (k2 > bv) { bv = k2; bi = base + 2; }                    \
            if (k3 > bv) { bv = k3; bi = base + 3; }                    \
        }                                                               \
    }

// Consume batch JC -- greedy path.
#define CONS_G(LC, JC)                                                  \
    {                                                                   \
        const int f = t + (JC) * TPB;                                   \
        if (f < V4c) {                                                  \
            const int base = (gbase + f) << 2;                          \
            if (LC.x > bv) { bv = LC.x; bi = base;     }                \
            if (LC.y > bv) { bv = LC.y; bi = base + 1; }                \
            if (LC.z > bv) { bv = LC.z; bi = base + 2; }                \
            if (LC.w > bv) { bv = LC.w; bi = base + 3; }                \
        }                                                               \
    }

__global__ __launch_bounds__(TPB, 8) void sampler_phase1(
    const float* __restrict__ logits,
    const float* __restrict__ temps,
    const float* __restrict__ noise,
    float* __restrict__ ws_val,
    int* __restrict__ ws_idx, int V)
{
    const int chunk = blockIdx.x & (CHUNKS - 1);
    const int b     = blockIdx.x / CHUNKS;
    const int V4    = V >> 2;               // 32064
    const int V4c   = V4 / CHUNKS;          // 4008 (V divisible by 32)
    const int gbase = chunk * V4c;          // this chunk's first float4 index
    const float temp = temps[b];
    const v4f* __restrict__ lg4 =
        (const v4f*)(logits + (size_t)b * V) + gbase;
    const v4f* __restrict__ nz4 =
        (const v4f*)(noise + (size_t)b * V) + gbase;
    const int t    = threadIdx.x;
    const int last = V4c - 1;
    const int NIT  = (V4c + TPB - 1) / TPB;     // 16 for V=128256
    const int NIT4 = (NIT + 3) & ~3;            // pipeline works in groups of 4

    float bv = -INFINITY;
    int   bi = 0x7fffffff;

    if (temp == 0.0f) {
        // Greedy: argmax of raw logits, no noise traffic.
        v4f A0, A1, A2, A3;
        ISSUE1(A0, 0);
        ISSUE1(A1, 1);
        ISSUE1(A2, 2);
        for (int j = 0; j < NIT4; j += 4) {
            ISSUE1(A3, j + 3); WAITV(3); CONS_G(A0, j + 0);
            ISSUE1(A0, j + 4); WAITV(3); CONS_G(A1, j + 1);
            ISSUE1(A1, j + 5); WAITV(3); CONS_G(A2, j + 2);
            ISSUE1(A2, j + 6); WAITV(3); CONS_G(A3, j + 3);
        }
        // Drain; inputs pin buffer registers live until all loads returned.
        asm volatile("s_waitcnt vmcnt(0)"
                     :: "v"(A0), "v"(A1), "v"(A2), "v"(A3) : "memory");
        __builtin_amdgcn_sched_barrier(0);
    } else {
        const float c = (1.0f / temp) * 1.4426950408889634f;  // invT / ln2
        v4f L0, L1, L2, L3, U0, U1, U2, U3;
        ISSUE2(L0, U0, 0);
        ISSUE2(L1, U1, 1);
        ISSUE2(L2, U2, 2);
        for (int j = 0; j < NIT4; j += 4) {
            ISSUE2(L3, U3, j + 3); WAITV(6); CONS_S(L0, U0, j + 0);
            ISSUE2(L0, U0, j + 4); WAITV(6); CONS_S(L1, U1, j + 1);
            ISSUE2(L1, U1, j + 5); WAITV(6); CONS_S(L2, U2, j + 2);
            ISSUE2(L2, U2, j + 6); WAITV(6); CONS_S(L3, U3, j + 3);
        }
        asm volatile("s_waitcnt vmcnt(0)"
                     :: "v"(L0), "v"(U0), "v"(L1), "v"(U1),
                        "v"(L2), "v"(U2), "v"(L3), "v"(U3) : "memory");
        __builtin_amdgcn_sched_barrier(0);
    }

    // wave (64-lane) shuffle reduction, lowest-index tie-break
    #pragma unroll
    for (int off = 32; off > 0; off >>= 1) {
        const float ov = __shfl_down(bv, off);
        const int   oi = __shfl_down(bi, off);
        amax_comb(ov, oi, bv, bi);
    }

    __shared__ float s_v[TPB / 64];
    __shared__ int   s_i[TPB / 64];
    const int lane = t & 63;
    const int wave = t >> 6;
    if (lane == 0) { s_v[wave] = bv; s_i[wave] = bi; }
    __syncthreads();
    if (t == 0) {
        #pragma unroll
        for (int w = 1; w < TPB / 64; ++w) amax_comb(s_v[w], s_i[w], bv, bi);
        ws_val[blockIdx.x] = bv;
        ws_idx[blockIdx.x] = bi;
    }
}

__global__ void sampler_phase2(const float* __restrict__ ws_val,
                               const int* __restrict__ ws_idx,
                               int* __restrict__ out, int B)
{
    const int b = blockIdx.x * blockDim.x + threadIdx.x;
    if (b >= B) return;
    float bv = -INFINITY;
    int   bi = 0x7fffffff;
    #pragma unroll
    for (int c = 0; c < CHUNKS; ++c) {
        const float v = ws_val[b * CHUNKS + c];
        const int   i = ws_idx[b * CHUNKS + c];
        // chunk-ascending iteration + strict-> keeps lowest index on ties
        if (v > bv || (v == bv && i < bi)) { bv = v; bi = i; }
    }
    out[b] = bi;
}

extern "C" void kernel_launch(void* const* d_in, const int* in_sizes, int n_in,
                              void* d_out, int out_size, void* d_ws, size_t ws_size,
                              hipStream_t stream) {
    const float* logits = (const float*)d_in[0];   // [B, V] fp32
    const float* temps  = (const float*)d_in[1];   // [B]    fp32
    const float* noise  = (const float*)d_in[2];   // [B, V] fp32
    int* out = (int*)d_out;                        // [B]    int32
    const int B = in_sizes[1];
    const int V = in_sizes[0] / B;

    float* ws_val = (float*)d_ws;                  // [B*CHUNKS]
    int*   ws_idx = (int*)d_ws + (size_t)B * CHUNKS;

    sampler_phase1<<<B * CHUNKS, TPB, 0, stream>>>(logits, temps, noise,
                                                   ws_val, ws_idx, V);
    sampler_phase2<<<(B + 255) / 256, 256, 0, stream>>>(ws_val, ws_idx, out, B);
}

// Round 8
// 244.739 us; speedup vs baseline: 1.1165x; 1.1165x over previous
//
#include <hip/hip_runtime.h>
#include <math.h>

// Sampler: B=256 rows, V=128256 vocab.
// out[b] = (T[b]==0) ? argmax(logits[b,:])
//                    : argmax(logits[b,:]/T[b] - log(-log1p(-noise[b,:])))
// Log-space Gumbel-max (softmax denom + row-max cancel), all in log2 so each
// log is one HW v_log_f32.
//
// FINAL (R12 = R9 verbatim).  Optimization history / why this is terminal:
//   cache-mode matrix (the decisive axis):
//     cached loads        2.58 TB/s   (R0-R7: L1+L2 allocate wall)
//     sc0 (L2-allocate)   2.58 TB/s   (R11: wall is allocation, not L1)
//     nt  (no allocate)   3.5-3.6 TB/s  <-- this kernel
//     global_load_lds DMA 2.4-2.5 TB/s (R7/R10: shared request pool)
//   depth: null (R6 asm vmcnt(6) pipeline = at-use; R9 nt pipeline = +2.5us)
//   path:  null (R10 hybrid VGPR||DMA slightly negative -> shared pool)
//   shape: null (TPB 1024/512/256, CHUNKS 4/8 all equal)
//   source: null (all-L3-hit dispatches run same speed as HBM dispatches)
// Phase1 pure-read 246MB @ ~69us = 3.57 TB/s -- exceeds resident
// copyBuffer's 3.45 TB/s total-moved and the read half of the 6.29 TB/s
// copy ceiling.  Remaining dur is harness re-poison fill (2x76us) +
// phase2/launch overhead.  Zero-reuse 64B-granular reads on gfx950
// saturate at ~3.6 TB/s; nt (no L1/L2 allocation) is required to get there.

constexpr int TPB    = 256;
constexpr int CHUNKS = 8;

typedef float v4f __attribute__((ext_vector_type(4)));

__device__ __forceinline__ void amax_comb(float v, int i, float& bv, int& bi) {
    // np.argmax semantics: strictly greater wins; ties -> lowest index
    if (v > bv || (v == bv && i < bi)) { bv = v; bi = i; }
}

// key = l*c - log2(-log1p(-u)), c = invT/ln2.  Abs err ~1e-6, far below
// top-1/top-2 Gumbel key gaps.  u==0 -> en=0 -> -inf -> key=+inf, matching
// reference probs/0 = +inf (first-index tie-break both sides).
__device__ __forceinline__ float gumbel_key(float l, float u, float c) {
    // u >= 0.125: 1-u exact on the 2^-24 uniform grid, |log2(1-u)| >= 0.19
    const float w   = 1.0f - u;
    const float enw = __log2f(w) * -0.693147180559945f;   // -log(1-u)
    // u < 0.125: en/u = 1 + u/2 + u^2/3 + ... (trunc err < 6e-6 rel)
    float p = 0.16666667f;
    p = fmaf(p, u, 0.2f);
    p = fmaf(p, u, 0.25f);
    p = fmaf(p, u, 0.33333333f);
    p = fmaf(p, u, 0.5f);
    p = fmaf(p, u, 1.0f);
    const float en = (u < 0.125f) ? p * u : enw;
    return fmaf(l, c, -__log2f(en));
}

// Issue batch J: two async 16B nt loads into (LD, UD).  Opaque to the
// compiler: cannot be sunk, registers pinned, no L1/L2 allocation.
#define ISSUE2(LD, UD, J)                                               \
    {                                                                   \
        const int fi = min(t + (J) * TPB, last);                        \
        asm volatile("global_load_dwordx4 %0, %2, off nt\n\t"           \
                     "global_load_dwordx4 %1, %3, off nt"               \
                     : "=&v"(LD), "=&v"(UD)                             \
                     : "v"(lg4 + fi), "v"(nz4 + fi));                   \
    }

// Issue batch J: one async 16B nt load (greedy path, logits only).
#define ISSUE1(LD, J)                                                   \
    {                                                                   \
        const int fi = min(t + (J) * TPB, last);                        \
        asm volatile("global_load_dwordx4 %0, %1, off nt"               \
                     : "=&v"(LD) : "v"(lg4 + fi));                      \
    }

// Counted wait: oldest loads retired, N newest still in flight.  The
// sched_barrier stops the compiler hoisting the consume VALU above the wait.
#define WAITV(N)                                                        \
    asm volatile("s_waitcnt vmcnt(" #N ")" ::: "memory");               \
    __builtin_amdgcn_sched_barrier(0)

// Consume batch JC from (LC, UC) -- sampled path.
#define CONS_S(LC, UC, JC)                                              \
    {                                                                   \
        const int f = t + (JC) * TPB;                                   \
        if (f < V4c) {                                                  \
            const int base = (gbase + f) << 2;                          \
            const float k0 = gumbel_key(LC.x, UC.x, c);                 \
            const float k1 = gumbel_key(LC.y, UC.y, c);                 \
            const float k2 = gumbel_key(LC.z, UC.z, c);                 \
            const float k3 = gumbel_key(LC.w, UC.w, c);                 \
            if (k0 > bv) { bv = k0; bi = base;     }                    \
            if (k1 > bv) { bv = k1; bi = base + 1; }                    \
            if (k2 > bv) { bv = k2; bi = base + 2; }                    \
            if (k3 > bv) { bv = k3; bi = base + 3; }                    \
        }                                                               \
    }

// Consume batch JC -- greedy path.
#define CONS_G(LC, JC)                                                  \
    {                                                                   \
        const int f = t + (JC) * TPB;                                   \
        if (f < V4c) {                                                  \
            const int base = (gbase + f) << 2;                          \
            if (LC.x > bv) { bv = LC.x; bi = base;     }                \
            if (LC.y > bv) { bv = LC.y; bi = base + 1; }                \
            if (LC.z > bv) { bv = LC.z; bi = base + 2; }                \
            if (LC.w > bv) { bv = LC.w; bi = base + 3; }                \
        }                                                               \
    }

__global__ __launch_bounds__(TPB, 8) void sampler_phase1(
    const float* __restrict__ logits,
    const float* __restrict__ temps,
    const float* __restrict__ noise,
    float* __restrict__ ws_val,
    int* __restrict__ ws_idx, int V)
{
    const int chunk = blockIdx.x & (CHUNKS - 1);
    const int b     = blockIdx.x / CHUNKS;
    const int V4    = V >> 2;               // 32064
    const int V4c   = V4 / CHUNKS;          // 4008 (V divisible by 32)
    const int gbase = chunk * V4c;          // this chunk's first float4 index
    const float temp = temps[b];
    const v4f* __restrict__ lg4 =
        (const v4f*)(logits + (size_t)b * V) + gbase;
    const v4f* __restrict__ nz4 =
        (const v4f*)(noise + (size_t)b * V) + gbase;
    const int t    = threadIdx.x;
    const int last = V4c - 1;
    const int NIT  = (V4c + TPB - 1) / TPB;     // 16 for V=128256
    const int NIT4 = (NIT + 3) & ~3;            // pipeline works in groups of 4

    float bv = -INFINITY;
    int   bi = 0x7fffffff;

    if (temp == 0.0f) {
        // Greedy: argmax of raw logits, no noise traffic.
        v4f A0, A1, A2, A3;
        ISSUE1(A0, 0);
        ISSUE1(A1, 1);
        ISSUE1(A2, 2);
        for (int j = 0; j < NIT4; j += 4) {
            ISSUE1(A3, j + 3); WAITV(3); CONS_G(A0, j + 0);
            ISSUE1(A0, j + 4); WAITV(3); CONS_G(A1, j + 1);
            ISSUE1(A1, j + 5); WAITV(3); CONS_G(A2, j + 2);
            ISSUE1(A2, j + 6); WAITV(3); CONS_G(A3, j + 3);
        }
        // Drain; inputs pin buffer registers live until all loads returned.
        asm volatile("s_waitcnt vmcnt(0)"
                     :: "v"(A0), "v"(A1), "v"(A2), "v"(A3) : "memory");
        __builtin_amdgcn_sched_barrier(0);
    } else {
        const float c = (1.0f / temp) * 1.4426950408889634f;  // invT / ln2
        v4f L0, L1, L2, L3, U0, U1, U2, U3;
        ISSUE2(L0, U0, 0);
        ISSUE2(L1, U1, 1);
        ISSUE2(L2, U2, 2);
        for (int j = 0; j < NIT4; j += 4) {
            ISSUE2(L3, U3, j + 3); WAITV(6); CONS_S(L0, U0, j + 0);
            ISSUE2(L0, U0, j + 4); WAITV(6); CONS_S(L1, U1, j + 1);
            ISSUE2(L1, U1, j + 5); WAITV(6); CONS_S(L2, U2, j + 2);
            ISSUE2(L2, U2, j + 6); WAITV(6); CONS_S(L3, U3, j + 3);
        }
        asm volatile("s_waitcnt vmcnt(0)"
                     :: "v"(L0), "v"(U0), "v"(L1), "v"(U1),
                        "v"(L2), "v"(U2), "v"(L3), "v"(U3) : "memory");
        __builtin_amdgcn_sched_barrier(0);
    }

    // wave (64-lane) shuffle reduction, lowest-index tie-break
    #pragma unroll
    for (int off = 32; off > 0; off >>= 1) {
        const float ov = __shfl_down(bv, off);
        const int   oi = __shfl_down(bi, off);
        amax_comb(ov, oi, bv, bi);
    }

    __shared__ float s_v[TPB / 64];
    __shared__ int   s_i[TPB / 64];
    const int lane = t & 63;
    const int wave = t >> 6;
    if (lane == 0) { s_v[wave] = bv; s_i[wave] = bi; }
    __syncthreads();
    if (t == 0) {
        #pragma unroll
        for (int w = 1; w < TPB / 64; ++w) amax_comb(s_v[w], s_i[w], bv, bi);
        ws_val[blockIdx.x] = bv;
        ws_idx[blockIdx.x] = bi;
    }
}

__global__ void sampler_phase2(const float* __restrict__ ws_val,
                               const int* __restrict__ ws_idx,
                               int* __restrict__ out, int B)
{
    const int b = blockIdx.x * blockDim.x + threadIdx.x;
    if (b >= B) return;
    float bv = -INFINITY;
    int   bi = 0x7fffffff;
    #pragma unroll
    for (int c = 0; c < CHUNKS; ++c) {
        const float v = ws_val[b * CHUNKS + c];
        const int   i = ws_idx[b * CHUNKS + c];
        // chunk-ascending iteration + strict-> keeps lowest index on ties
        if (v > bv || (v == bv && i < bi)) { bv = v; bi = i; }
    }
    out[b] = bi;
}

extern "C" void kernel_launch(void* const* d_in, const int* in_sizes, int n_in,
                              void* d_out, int out_size, void* d_ws, size_t ws_size,
                              hipStream_t stream) {
    const float* logits = (const float*)d_in[0];   // [B, V] fp32
    const float* temps  = (const float*)d_in[1];   // [B]    fp32
    const float* noise  = (const float*)d_in[2];   // [B, V] fp32
    int* out = (int*)d_out;                        // [B]    int32
    const int B = in_sizes[1];
    const int V = in_sizes[0] / B;

    float* ws_val = (float*)d_ws;                  // [B*CHUNKS]
    int*   ws_idx = (int*)d_ws + (size_t)B * CHUNKS;

    sampler_phase1<<<B * CHUNKS, TPB, 0, stream>>>(logits, temps, noise,
                                                   ws_val, ws_idx, V);
    sampler_phase2<<<(B + 255) / 256, 256, 0, stream>>>(ws_val, ws_idx, out, B);
}